// Round 4
// baseline (342.803 us; speedup 1.0000x reference)
//
#include <hip/hip_runtime.h>
#include <hip/hip_bf16.h>

typedef __hip_bfloat16 bf16;
typedef __attribute__((ext_vector_type(8))) short short8;
typedef __attribute__((ext_vector_type(4))) float f32x4;
typedef __attribute__((ext_vector_type(4), aligned(4))) int i32x4u;
typedef __attribute__((ext_vector_type(4), aligned(4))) float f32x4u;
typedef __attribute__((ext_vector_type(4))) int i32x4;

__device__ __forceinline__ float b2f(bf16 v) { return __bfloat162float(v); }
// int (2 packed bf16) -> two floats. x = low half, y = high half.
__device__ __forceinline__ float2 i2f2(int w) {
  float lo = __uint_as_float(((unsigned)w) << 16);
  float hi = __uint_as_float(((unsigned)w) & 0xFFFF0000u);
  return make_float2(lo, hi);
}
// float -> bf16 bits (RNE; inputs finite)
__device__ __forceinline__ unsigned f2bfb(float f) {
  unsigned u = __float_as_uint(f);
  unsigned r = 0x7FFFu + ((u >> 16) & 1u);
  return (u + r) >> 16;
}
__device__ __forceinline__ unsigned pk2(float a, float b) {
  return f2bfb(a) | (f2bfb(b) << 16);
}
__device__ __forceinline__ float ldv(const void* p, int i, int f) {
  return f ? ((const float*)p)[i] : b2f(((const bf16*)p)[i]);
}

#define SH 392  // stage row stride in halfs (384 + 8 pad, 16B-aligned)

// ------------------------------------------------------------------
// weight materialization + per-block dtype detect + counts zero;
// block 0 computes s_et and publishes flag.
// ------------------------------------------------------------------
__global__ __launch_bounds__(256) void wconv_kernel(
    const void* __restrict__ ee, const void* __restrict__ w1,
    const void* __restrict__ a1, const void* __restrict__ eu1,
    const void* __restrict__ b1, const void* __restrict__ w2,
    const void* __restrict__ a2, const void* __restrict__ eu2,
    const void* __restrict__ b2, int* __restrict__ flag,
    float* __restrict__ eef, float* __restrict__ att1f, float* __restrict__ att2f,
    float* __restrict__ b1f, float* __restrict__ b2f,
    bf16* __restrict__ WT1, bf16* __restrict__ WT2,
    bf16* __restrict__ euT1, bf16* __restrict__ euT2,
    float* __restrict__ s_et, int* __restrict__ counts, int N) {
  __shared__ int cnt;
  __shared__ int fl;
  if (threadIdx.x == 0) cnt = 0;
  __syncthreads();
  const unsigned short* probe = (const unsigned short*)w1;
  int local = 0;
#pragma unroll
  for (int k = 0; k < 8; ++k) {
    int e = (probe[threadIdx.x * 8 + k] >> 7) & 0xFF;
    if (e >= 160) local++;
  }
  if (local) atomicAdd(&cnt, local);
  __syncthreads();
  if (threadIdx.x == 0) {
    fl = (cnt > 16) ? 1 : 0;
    if (blockIdx.x == 0) *flag = fl;
  }
  __syncthreads();
  int f = fl;

  int i = blockIdx.x * 256 + threadIdx.x;
  if (i < 2048) {
    eef[i] = ldv(ee, i, f);
  } else if (i < 2912) {
    att1f[i - 2048] = ldv(a1, i - 2048, f);
  } else if (i < 3776) {
    att2f[i - 2912] = ldv(a2, i - 2912, f);
  } else if (i < 3904) {
    b1f[i - 3776] = ldv(b1, i - 3776, f);
  } else if (i < 4032) {
    b2f[i - 3904] = ldv(b2, i - 3904, f);
  } else if (i < 53184) {
    int j = i - 4032; int c = j >> 7, k = j & 127;
    WT1[j] = __float2bfloat16(ldv(w1, k * 384 + c, f));
  } else if (i < 102336) {
    int j = i - 53184; int c = j >> 7, k = j & 127;
    WT2[j] = __float2bfloat16(ldv(w2, k * 384 + c, f));
  } else if (i < 122816) {
    int j = i - 102336; int c = j / 160, k = j % 160;
    euT1[j] = __float2bfloat16(ldv(eu1, k * 128 + c, f));
  } else if (i < 143296) {
    int j = i - 122816; int c = j / 160, k = j % 160;
    euT2[j] = __float2bfloat16(ldv(eu2, k * 128 + c, f));
  } else if (i < 143296 + N) {
    counts[i - 143296] = 0;
  }

  if (blockIdx.x == 0) {
    for (int id = threadIdx.x; id < 2 * 65 * 3; id += 256) {
      int l = id / (65 * 3);
      int r = id % (65 * 3);
      int t = r / 3, h = r % 3;
      const void* att = l ? a2 : a1;
      float s = 0.0f;
      if (t < 64) {
        for (int d = 0; d < 32; ++d)
          s += ldv(ee, t * 32 + d, f) * ldv(att, h * 288 + 256 + d, f);
      }
      s_et[id] = s;
    }
  }
}

// ------------------------------------------------------------------
// prep: x0 = maxnorm(node_emb[x_idx]) -> bf16 x (in d_out);
// + edge counting (grid-stride). counts pre-zeroed by wconv.
// ------------------------------------------------------------------
__global__ __launch_bounds__(256) void prep_kernel(
    const int* __restrict__ x_idx, const void* __restrict__ node_emb,
    const int* __restrict__ flag, bf16* __restrict__ xb,
    int* __restrict__ counts, const int* __restrict__ dst, int E0, int N) {
  int wid = threadIdx.x >> 6, lane = threadIdx.x & 63;
  int n = blockIdx.x * 4 + wid;
  if (n < N) {
    int idx = x_idx[n];
    if ((unsigned)idx >= (unsigned)N) idx = 0;
    float v0, v1;
    if (*flag) {
      const float* er = (const float*)node_emb + (size_t)idx * 128;
      v0 = er[lane]; v1 = er[lane + 64];
    } else {
      const bf16* er = (const bf16*)node_emb + (size_t)idx * 128;
      v0 = b2f(er[lane]); v1 = b2f(er[lane + 64]);
    }
    float ss = v0 * v0 + v1 * v1;
#pragma unroll
    for (int d = 32; d > 0; d >>= 1) ss += __shfl_xor(ss, d);
    float norm = sqrtf(ss);
    float scale = norm > 1.0f ? 1.0f / norm : 1.0f;
    xb[(size_t)n * 128 + lane] = __float2bfloat16(v0 * scale);
    xb[(size_t)n * 128 + 64 + lane] = __float2bfloat16(v1 * scale);
  }
  int gid = blockIdx.x * 256 + threadIdx.x;
  int stride = gridDim.x * 256;
  for (int i = gid; i < E0; i += stride) {
    int d = dst[i];
    if ((unsigned)d >= (unsigned)N) d = 0;
    atomicAdd(&counts[d], 1);
  }
}

// ------------------------------------------------------------------
// parallel exclusive scan with +1 per row (self loop), one block of
// 1024 threads (16 waves). counts becomes cursor in place.
// ------------------------------------------------------------------
__global__ __launch_bounds__(1024) void scan_kernel(
    int* __restrict__ counts, int* __restrict__ row_ptr, int N) {
  __shared__ int wsum[16];
  int t = threadIdx.x;
  int chunk = (N + 1023) >> 10;
  int lo = t * chunk;
  int hi = lo + chunk;
  if (lo > N) lo = N;
  if (hi > N) hi = N;
  int s = 0;
  for (int i = lo; i < hi; ++i) s += counts[i] + 1;
  int lane = t & 63, wv = t >> 6;
  int incl = s;
#pragma unroll
  for (int d = 1; d < 64; d <<= 1) {
    int u = __shfl_up(incl, d);
    if (lane >= d) incl += u;
  }
  if (lane == 63) wsum[wv] = incl;
  __syncthreads();
  if (t == 0) {
    int run = 0;
#pragma unroll
    for (int w = 0; w < 16; ++w) { int c = wsum[w]; wsum[w] = run; run += c; }
  }
  __syncthreads();
  int run = incl - s + wsum[wv];  // exclusive prefix for this thread
  for (int i = lo; i < hi; ++i) {
    int c = counts[i] + 1;
    row_ptr[i] = run;
    counts[i] = run;
    run += c;
  }
  if (t == 1023) row_ptr[N] = run;
}

// ------------------------------------------------------------------
// scatter edges (+self loops, etype=64) into CSR: packed = src | et<<16
// ------------------------------------------------------------------
__global__ __launch_bounds__(256) void scatter_kernel(
    const int* __restrict__ src, const int* __restrict__ dst,
    const int* __restrict__ et, int* __restrict__ cursor,
    int* __restrict__ packed, int E0, int N) {
  int E = E0 + N;
  int i = blockIdx.x * blockDim.x + threadIdx.x;
  if (i < E0) {
    int d = dst[i];
    if ((unsigned)d >= (unsigned)N) d = 0;
    int p = atomicAdd(&cursor[d], 1);
    if ((unsigned)p >= (unsigned)E) p = 0;
    int t = et[i] & 63;
    packed[p] = (src[i] & 0xFFFF) | (t << 16);
  } else if (i < E) {
    int n = i - E0;
    int p = atomicAdd(&cursor[n], 1);
    if ((unsigned)p >= (unsigned)E) p = 0;
    packed[p] = (n & 0xFFFF) | (64 << 16);
  }
}

// ------------------------------------------------------------------
// xh = x @ W via MFMA + fused s_i/s_j (layer 0; x = bf16 in d_out).
// Block = 6 waves (384 thr), 32 rows x 384 cols. Grid: N/32.
// xh permuted (half-index = node*384 + pair*6 + head*2 + sub) staged
// in LDS, written out as contiguous 16B chunks.
// ------------------------------------------------------------------
__global__ __launch_bounds__(384) void gemm_xh_s_mfma(
    const bf16* __restrict__ x, const bf16* __restrict__ WT,
    const float* __restrict__ attf, bf16* __restrict__ xh,
    float* __restrict__ s_i, float* __restrict__ s_j, int N) {
  __shared__ __align__(16) bf16 stage[32 * SH];
  __shared__ float lds_i[6][32];
  __shared__ float lds_j[6][32];
  int wave = threadIdx.x >> 6, lane = threadIdx.x & 63;
  int row_base = blockIdx.x * 32;
  int quad = lane >> 4, r16 = lane & 15;
  int rowA = row_base + r16;      if (rowA >= N) rowA = N - 1;
  int rowB = row_base + 16 + r16; if (rowB >= N) rowB = N - 1;
  const short8* apA = (const short8*)(x + (size_t)rowA * 128 + quad * 8);
  const short8* apB = (const short8*)(x + (size_t)rowB * 128 + quad * 8);
  short8 aA[4], aB[4];
#pragma unroll
  for (int kk = 0; kk < 4; ++kk) { aA[kk] = apA[kk * 4]; aB[kk] = apB[kk * 4]; }

  float piA[4] = {0.f, 0.f, 0.f, 0.f}, pjA[4] = {0.f, 0.f, 0.f, 0.f};
  float piB[4] = {0.f, 0.f, 0.f, 0.f}, pjB[4] = {0.f, 0.f, 0.f, 0.f};
#pragma unroll
  for (int j = 0; j < 4; ++j) {
    int col = wave * 64 + j * 16 + r16;
    const short8* bp = (const short8*)(WT + (size_t)col * 128 + quad * 8);
    short8 b[4];
#pragma unroll
    for (int kk = 0; kk < 4; ++kk) b[kk] = bp[kk * 4];
    f32x4 accA = {0.f, 0.f, 0.f, 0.f};
    f32x4 accB = {0.f, 0.f, 0.f, 0.f};
#pragma unroll
    for (int kk = 0; kk < 4; ++kk) {
      accA = __builtin_amdgcn_mfma_f32_16x16x32_bf16(aA[kk], b[kk], accA, 0, 0, 0);
      accB = __builtin_amdgcn_mfma_f32_16x16x32_bf16(aB[kk], b[kk], accB, 0, 0, 0);
    }
    int h = col >> 7, fi = col & 127, pair = fi >> 1, sub = fi & 1;
    int base = pair * 6 + h * 2 + sub;
#pragma unroll
    for (int r = 0; r < 4; ++r) {
      stage[(quad * 4 + r) * SH + base] = __float2bfloat16(accA[r]);
      stage[(16 + quad * 4 + r) * SH + base] = __float2bfloat16(accB[r]);
    }
    float ai = attf[h * 288 + fi];
    float aj = attf[h * 288 + 128 + fi];
#pragma unroll
    for (int r = 0; r < 4; ++r) {
      piA[r] = fmaf(accA[r], ai, piA[r]);
      pjA[r] = fmaf(accA[r], aj, pjA[r]);
      piB[r] = fmaf(accB[r], ai, piB[r]);
      pjB[r] = fmaf(accB[r], aj, pjB[r]);
    }
  }
#pragma unroll
  for (int d = 1; d < 16; d <<= 1) {
#pragma unroll
    for (int r = 0; r < 4; ++r) {
      piA[r] += __shfl_xor(piA[r], d);
      pjA[r] += __shfl_xor(pjA[r], d);
      piB[r] += __shfl_xor(piB[r], d);
      pjB[r] += __shfl_xor(pjB[r], d);
    }
  }
  if (r16 == 0) {
#pragma unroll
    for (int r = 0; r < 4; ++r) {
      lds_i[wave][quad * 4 + r] = piA[r];
      lds_j[wave][quad * 4 + r] = pjA[r];
      lds_i[wave][16 + quad * 4 + r] = piB[r];
      lds_j[wave][16 + quad * 4 + r] = pjB[r];
    }
  }
  __syncthreads();
  int m = threadIdx.x;
  if (m < 96) {
    int h = m / 32, r = m % 32;
    int node = row_base + r;
    if (node < N) s_i[node * 3 + h] = lds_i[2 * h][r] + lds_i[2 * h + 1][r];
  } else if (m < 192) {
    int tt = m - 96;
    int h = tt / 32, r = tt % 32;
    int node = row_base + r;
    if (node < N) s_j[node * 3 + h] = lds_j[2 * h][r] + lds_j[2 * h + 1][r];
  }
  // contiguous copy-out: 32 rows x 48 chunks of 16B
#pragma unroll
  for (int k = 0; k < 4; ++k) {
    int c = threadIdx.x + k * 384;
    int r = c / 48, o = c % 48;
    int node = row_base + r;
    if (node < N)
      *(i32x4*)(xh + (size_t)node * 384 + o * 8) =
          *(const i32x4*)(stage + r * SH + o * 8);
  }
}

// ------------------------------------------------------------------
// FOX: fused layer boundary. Phase 1: out = aggr @ euw + bias (+ELU),
// 16x128 bf16 tile in LDS. Phase 2: xh' = out @ W via MFMA (A from
// LDS) + fused s_i/s_j; xh' staged in LDS, contiguous copy-out.
// Grid N/16, 384 threads.
// ------------------------------------------------------------------
__global__ __launch_bounds__(384) void fox_kernel(
    const bf16* __restrict__ aggr, const bf16* __restrict__ euwT,
    const float* __restrict__ biasf, int do_elu,
    const bf16* __restrict__ WT, const float* __restrict__ attf,
    bf16* __restrict__ xh, float* __restrict__ s_i, float* __restrict__ s_j,
    int N) {
  __shared__ bf16 xtile[16][136];  // [m][k], row stride 272 B
  __shared__ __align__(16) bf16 stage[16 * SH];
  __shared__ float lds_i[6][16];
  __shared__ float lds_j[6][16];
  int wave = threadIdx.x >> 6, lane = threadIdx.x & 63;
  int quad = lane >> 4, r16 = lane & 15;
  int row_base = blockIdx.x * 16;
  int row = row_base + r16; if (row >= N) row = N - 1;

  // ---- phase 1: out tile (K=160) ----
  const short8* ap = (const short8*)(aggr + (size_t)row * 160 + quad * 8);
  short8 aa[5];
#pragma unroll
  for (int kk = 0; kk < 5; ++kk) aa[kk] = ap[kk * 4];
  for (int t = wave; t < 8; t += 6) {
    int col = t * 16 + r16;
    const short8* bp = (const short8*)(euwT + (size_t)col * 160 + quad * 8);
    f32x4 acc = {0.f, 0.f, 0.f, 0.f};
#pragma unroll
    for (int kk = 0; kk < 5; ++kk)
      acc = __builtin_amdgcn_mfma_f32_16x16x32_bf16(aa[kk], bp[kk * 4], acc, 0, 0, 0);
    float bv = biasf[col];
#pragma unroll
    for (int r = 0; r < 4; ++r) {
      float v = acc[r] + bv;
      if (do_elu) v = v > 0.0f ? v : expm1f(v);
      xtile[quad * 4 + r][col] = __float2bfloat16(v);
    }
  }
  __syncthreads();

  // ---- phase 2: xh' = xtile @ W (K=128), A from LDS ----
  short8 a[4];
#pragma unroll
  for (int kk = 0; kk < 4; ++kk)
    a[kk] = *(const short8*)(&xtile[r16][quad * 8 + kk * 32]);

  float pi_r[4] = {0.f, 0.f, 0.f, 0.f};
  float pj_r[4] = {0.f, 0.f, 0.f, 0.f};
#pragma unroll
  for (int j = 0; j < 4; ++j) {
    int col = wave * 64 + j * 16 + r16;
    const short8* bp = (const short8*)(WT + (size_t)col * 128 + quad * 8);
    f32x4 acc = {0.f, 0.f, 0.f, 0.f};
#pragma unroll
    for (int kk = 0; kk < 4; ++kk)
      acc = __builtin_amdgcn_mfma_f32_16x16x32_bf16(a[kk], bp[kk * 4], acc, 0, 0, 0);
    int h = col >> 7, fi = col & 127, pair = fi >> 1, sub = fi & 1;
    int base = pair * 6 + h * 2 + sub;
#pragma unroll
    for (int r = 0; r < 4; ++r)
      stage[(quad * 4 + r) * SH + base] = __float2bfloat16(acc[r]);
    float ai = attf[h * 288 + fi];
    float aj = attf[h * 288 + 128 + fi];
#pragma unroll
    for (int r = 0; r < 4; ++r) {
      pi_r[r] = fmaf(acc[r], ai, pi_r[r]);
      pj_r[r] = fmaf(acc[r], aj, pj_r[r]);
    }
  }
#pragma unroll
  for (int d = 1; d < 16; d <<= 1) {
#pragma unroll
    for (int r = 0; r < 4; ++r) {
      pi_r[r] += __shfl_xor(pi_r[r], d);
      pj_r[r] += __shfl_xor(pj_r[r], d);
    }
  }
  if (r16 == 0) {
#pragma unroll
    for (int r = 0; r < 4; ++r) {
      lds_i[wave][quad * 4 + r] = pi_r[r];
      lds_j[wave][quad * 4 + r] = pj_r[r];
    }
  }
  __syncthreads();
  int m = threadIdx.x;
  if (m < 48) {
    int h = m / 16, r = m % 16;
    int node = row_base + r;
    if (node < N) s_i[node * 3 + h] = lds_i[2 * h][r] + lds_i[2 * h + 1][r];
  } else if (m < 96) {
    int tt = m - 48;
    int h = tt / 16, r = tt % 16;
    int node = row_base + r;
    if (node < N) s_j[node * 3 + h] = lds_j[2 * h][r] + lds_j[2 * h + 1][r];
  }
  // contiguous copy-out: 16 rows x 48 chunks of 16B
#pragma unroll
  for (int k = 0; k < 2; ++k) {
    int c = threadIdx.x + k * 384;
    int r = c / 48, o = c % 48;
    int node = row_base + r;
    if (node < N)
      *(i32x4*)(xh + (size_t)node * 384 + o * 8) =
          *(const i32x4*)(stage + r * SH + o * 8);
  }
}

// ------------------------------------------------------------------
// per-dst softmax + weighted aggregation -> bf16 aggr [N][160].
// 2 waves per node; partials combined via LDS. Per-edge gather is a
// single dwordx4 (12B used + 4B overlap); j-loop unrolled x4 for MLP.
// s_j fetched as one 4B-aligned dwordx4 (12B used).
// ------------------------------------------------------------------
__global__ __launch_bounds__(256) void edge_aggr_kernel(
    const int* __restrict__ xh_i, const float* __restrict__ s_i,
    const float* __restrict__ s_j, const float* __restrict__ s_et,
    const float2* __restrict__ eef2, const int* __restrict__ row_ptr,
    const int* __restrict__ packed, unsigned* __restrict__ aggr_u,
    int N, int E) {
  __shared__ float lds[2][512];
  int wid = threadIdx.x >> 6, lane = threadIdx.x & 63;
  int nodeLocal = wid >> 1, w = wid & 1;
  int n0 = blockIdx.x * 2 + nodeLocal;
  int n = n0 < N ? n0 : N - 1;
  int start = row_ptr[n], end = row_ptr[n + 1];
  if (start < 0) start = 0;
  if (start > E) start = E;
  if (end < start) end = start;
  if (end > E) end = E;
  int deg = end - start;
  float si0 = s_i[n * 3 + 0], si1 = s_i[n * 3 + 1], si2 = s_i[n * 3 + 2];

  float p0r = 0.f, p1r = 0.f, p2r = 0.f;
  int pkr = 0;
  float dp0 = 0.0f, dp1 = 0.0f, dp2 = 0.0f;
  int slot = 2 * lane + w;
  if (slot < deg) {
    int p = packed[start + slot];
    int s = p & 0xFFFF; if (s >= N) s = N - 1;
    int t = (p >> 16) & 127; if (t > 64) t = 64;
    f32x4u sj = *(const f32x4u*)(s_j + s * 3);
    float a0 = si0 + sj.x + s_et[t * 3 + 0];
    float a1 = si1 + sj.y + s_et[t * 3 + 1];
    float a2 = si2 + sj.z + s_et[t * 3 + 2];
    a0 = a0 > 0.0f ? a0 : 0.2f * a0;
    a1 = a1 > 0.0f ? a1 : 0.2f * a1;
    a2 = a2 > 0.0f ? a2 : 0.2f * a2;
    a0 = fminf(fmaxf(a0, -60.0f), 60.0f);
    a1 = fminf(fmaxf(a1, -60.0f), 60.0f);
    a2 = fminf(fmaxf(a2, -60.0f), 60.0f);
    p0r = __expf(a0); p1r = __expf(a1); p2r = __expf(a2);
    dp0 = p0r; dp1 = p1r; dp2 = p2r;
    pkr = s | (t << 16);
  }
#pragma unroll
  for (int d = 32; d > 0; d >>= 1) {
    dp0 += __shfl_xor(dp0, d);
    dp1 += __shfl_xor(dp1, d);
    dp2 += __shfl_xor(dp2, d);
  }
  float d0 = dp0, d1 = dp1, d2 = dp2;

  float2 ax0 = make_float2(0.f, 0.f), ax1 = ax0, ax2 = ax0;
  float2 ae0 = ax0, ae1 = ax0, ae2 = ax0;
  int capped = deg < 128 ? deg : 128;
  int cnt = (capped > w) ? ((capped - w + 1) >> 1) : 0;

  {
    int j = 0;
    for (; j + 4 <= cnt; j += 4) {
      int pkA = __shfl(pkr, j), pkB = __shfl(pkr, j + 1);
      int pkC = __shfl(pkr, j + 2), pkD = __shfl(pkr, j + 3);
      float qA0 = __shfl(p0r, j), qB0 = __shfl(p0r, j + 1);
      float qC0 = __shfl(p0r, j + 2), qD0 = __shfl(p0r, j + 3);
      float qA1 = __shfl(p1r, j), qB1 = __shfl(p1r, j + 1);
      float qC1 = __shfl(p1r, j + 2), qD1 = __shfl(p1r, j + 3);
      float qA2 = __shfl(p2r, j), qB2 = __shfl(p2r, j + 1);
      float qC2 = __shfl(p2r, j + 2), qD2 = __shfl(p2r, j + 3);
      int sA = pkA & 0xFFFF, tA = pkA >> 16;
      int sB = pkB & 0xFFFF, tB = pkB >> 16;
      int sC = pkC & 0xFFFF, tC = pkC >> 16;
      int sD = pkD & 0xFFFF, tD = pkD >> 16;
      i32x4u qA = *(const i32x4u*)(xh_i + (size_t)sA * 192 + lane * 3);
      i32x4u qB = *(const i32x4u*)(xh_i + (size_t)sB * 192 + lane * 3);
      i32x4u qC = *(const i32x4u*)(xh_i + (size_t)sC * 192 + lane * 3);
      i32x4u qD = *(const i32x4u*)(xh_i + (size_t)sD * 192 + lane * 3);
      float2 vA0 = i2f2(qA.x), vA1 = i2f2(qA.y), vA2 = i2f2(qA.z);
      float2 vB0 = i2f2(qB.x), vB1 = i2f2(qB.y), vB2 = i2f2(qB.z);
      float2 vC0 = i2f2(qC.x), vC1 = i2f2(qC.y), vC2 = i2f2(qC.z);
      float2 vD0 = i2f2(qD.x), vD1 = i2f2(qD.y), vD2 = i2f2(qD.z);
      ax0.x = fmaf(qA0, vA0.x, ax0.x); ax0.y = fmaf(qA0, vA0.y, ax0.y);
      ax1.x = fmaf(qA1, vA1.x, ax1.x); ax1.y = fmaf(qA1, vA1.y, ax1.y);
      ax2.x = fmaf(qA2, vA2.x, ax2.x); ax2.y = fmaf(qA2, vA2.y, ax2.y);
      ax0.x = fmaf(qB0, vB0.x, ax0.x); ax0.y = fmaf(qB0, vB0.y, ax0.y);
      ax1.x = fmaf(qB1, vB1.x, ax1.x); ax1.y = fmaf(qB1, vB1.y, ax1.y);
      ax2.x = fmaf(qB2, vB2.x, ax2.x); ax2.y = fmaf(qB2, vB2.y, ax2.y);
      ax0.x = fmaf(qC0, vC0.x, ax0.x); ax0.y = fmaf(qC0, vC0.y, ax0.y);
      ax1.x = fmaf(qC1, vC1.x, ax1.x); ax1.y = fmaf(qC1, vC1.y, ax1.y);
      ax2.x = fmaf(qC2, vC2.x, ax2.x); ax2.y = fmaf(qC2, vC2.y, ax2.y);
      ax0.x = fmaf(qD0, vD0.x, ax0.x); ax0.y = fmaf(qD0, vD0.y, ax0.y);
      ax1.x = fmaf(qD1, vD1.x, ax1.x); ax1.y = fmaf(qD1, vD1.y, ax1.y);
      ax2.x = fmaf(qD2, vD2.x, ax2.x); ax2.y = fmaf(qD2, vD2.y, ax2.y);
      if (lane < 16) {
        if (tA != 64) {
          float2 ev = eef2[tA * 16 + lane];
          ae0.x = fmaf(qA0, ev.x, ae0.x); ae0.y = fmaf(qA0, ev.y, ae0.y);
          ae1.x = fmaf(qA1, ev.x, ae1.x); ae1.y = fmaf(qA1, ev.y, ae1.y);
          ae2.x = fmaf(qA2, ev.x, ae2.x); ae2.y = fmaf(qA2, ev.y, ae2.y);
        }
        if (tB != 64) {
          float2 ev = eef2[tB * 16 + lane];
          ae0.x = fmaf(qB0, ev.x, ae0.x); ae0.y = fmaf(qB0, ev.y, ae0.y);
          ae1.x = fmaf(qB1, ev.x, ae1.x); ae1.y = fmaf(qB1, ev.y, ae1.y);
          ae2.x = fmaf(qB2, ev.x, ae2.x); ae2.y = fmaf(qB2, ev.y, ae2.y);
        }
        if (tC != 64) {
          float2 ev = eef2[tC * 16 + lane];
          ae0.x = fmaf(qC0, ev.x, ae0.x); ae0.y = fmaf(qC0, ev.y, ae0.y);
          ae1.x = fmaf(qC1, ev.x, ae1.x); ae1.y = fmaf(qC1, ev.y, ae1.y);
          ae2.x = fmaf(qC2, ev.x, ae2.x); ae2.y = fmaf(qC2, ev.y, ae2.y);
        }
        if (tD != 64) {
          float2 ev = eef2[tD * 16 + lane];
          ae0.x = fmaf(qD0, ev.x, ae0.x); ae0.y = fmaf(qD0, ev.y, ae0.y);
          ae1.x = fmaf(qD1, ev.x, ae1.x); ae1.y = fmaf(qD1, ev.y, ae1.y);
          ae2.x = fmaf(qD2, ev.x, ae2.x); ae2.y = fmaf(qD2, ev.y, ae2.y);
        }
      }
    }
    for (; j < cnt; ++j) {
      int pkA = __shfl(pkr, j);
      float qA0 = __shfl(p0r, j), qA1 = __shfl(p1r, j), qA2 = __shfl(p2r, j);
      int sA = pkA & 0xFFFF, tA = pkA >> 16;
      i32x4u qA = *(const i32x4u*)(xh_i + (size_t)sA * 192 + lane * 3);
      float2 vA0 = i2f2(qA.x), vA1 = i2f2(qA.y), vA2 = i2f2(qA.z);
      ax0.x = fmaf(qA0, vA0.x, ax0.x); ax0.y = fmaf(qA0, vA0.y, ax0.y);
      ax1.x = fmaf(qA1, vA1.x, ax1.x); ax1.y = fmaf(qA1, vA1.y, ax1.y);
      ax2.x = fmaf(qA2, vA2.x, ax2.x); ax2.y = fmaf(qA2, vA2.y, ax2.y);
      if (lane < 16 && tA != 64) {
        float2 ev = eef2[tA * 16 + lane];
        ae0.x = fmaf(qA0, ev.x, ae0.x); ae0.y = fmaf(qA0, ev.y, ae0.y);
        ae1.x = fmaf(qA1, ev.x, ae1.x); ae1.y = fmaf(qA1, ev.y, ae1.y);
        ae2.x = fmaf(qA2, ev.x, ae2.x); ae2.y = fmaf(qA2, ev.y, ae2.y);
      }
    }
  }

  if (w == 0) {
    for (int e = start + 128; e < end; ++e) {
      int p = packed[e];
      int s = p & 0xFFFF; if (s >= N) s = N - 1;
      int t = (p >> 16) & 127; if (t > 64) t = 64;
      f32x4u sj = *(const f32x4u*)(s_j + s * 3);
      float a0 = si0 + sj.x + s_et[t * 3 + 0];
      float a1 = si1 + sj.y + s_et[t * 3 + 1];
      float a2 = si2 + sj.z + s_et[t * 3 + 2];
      a0 = a0 > 0.0f ? a0 : 0.2f * a0;
      a1 = a1 > 0.0f ? a1 : 0.2f * a1;
      a2 = a2 > 0.0f ? a2 : 0.2f * a2;
      a0 = fminf(fmaxf(a0, -60.0f), 60.0f);
      a1 = fminf(fmaxf(a1, -60.0f), 60.0f);
      a2 = fminf(fmaxf(a2, -60.0f), 60.0f);
      float p0 = __expf(a0), p1 = __expf(a1), p2 = __expf(a2);
      d0 += p0; d1 += p1; d2 += p2;
      i32x4u q = *(const i32x4u*)(xh_i + (size_t)s * 192 + lane * 3);
      float2 v0 = i2f2(q.x), v1 = i2f2(q.y), v2 = i2f2(q.z);
      ax0.x = fmaf(p0, v0.x, ax0.x); ax0.y = fmaf(p0, v0.y, ax0.y);
      ax1.x = fmaf(p1, v1.x, ax1.x); ax1.y = fmaf(p1, v1.y, ax1.y);
      ax2.x = fmaf(p2, v2.x, ax2.x); ax2.y = fmaf(p2, v2.y, ax2.y);
      if (t != 64 && lane < 16) {
        float2 ev = eef2[t * 16 + lane];
        ae0.x = fmaf(p0, ev.x, ae0.x); ae0.y = fmaf(p0, ev.y, ae0.y);
        ae1.x = fmaf(p1, ev.x, ae1.x); ae1.y = fmaf(p1, ev.y, ae1.y);
        ae2.x = fmaf(p2, ev.x, ae2.x); ae2.y = fmaf(p2, ev.y, ae2.y);
      }
    }
  }

  float* L = lds[nodeLocal];
  if (w == 1) {
    L[lane * 2 + 0] = ax0.x;       L[lane * 2 + 1] = ax0.y;
    L[128 + lane * 2 + 0] = ax1.x; L[128 + lane * 2 + 1] = ax1.y;
    L[256 + lane * 2 + 0] = ax2.x; L[256 + lane * 2 + 1] = ax2.y;
    if (lane < 16) {
      L[384 + lane * 2 + 0] = ae0.x; L[384 + lane * 2 + 1] = ae0.y;
      L[416 + lane * 2 + 0] = ae1.x; L[416 + lane * 2 + 1] = ae1.y;
      L[448 + lane * 2 + 0] = ae2.x; L[448 + lane * 2 + 1] = ae2.y;
    }
    if (lane == 0) { L[480] = d0; L[481] = d1; L[482] = d2; }
  }
  __syncthreads();
  if (w == 0 && n0 < N) {
    ax0.x += L[lane * 2 + 0];       ax0.y += L[lane * 2 + 1];
    ax1.x += L[128 + lane * 2 + 0]; ax1.y += L[128 + lane * 2 + 1];
    ax2.x += L[256 + lane * 2 + 0]; ax2.y += L[256 + lane * 2 + 1];
    if (lane < 16) {
      ae0.x += L[384 + lane * 2 + 0]; ae0.y += L[384 + lane * 2 + 1];
      ae1.x += L[416 + lane * 2 + 0]; ae1.y += L[416 + lane * 2 + 1];
      ae2.x += L[448 + lane * 2 + 0]; ae2.y += L[448 + lane * 2 + 1];
    }
    d0 += L[480]; d1 += L[481]; d2 += L[482];
    const float third = 1.0f / 3.0f;
    float i0 = third / fmaxf(d0, 1e-30f);
    float i1 = third / fmaxf(d1, 1e-30f);
    float i2 = third / fmaxf(d2, 1e-30f);
    aggr_u[(size_t)n0 * 80 + lane] =
        pk2(ax0.x * i0 + ax1.x * i1 + ax2.x * i2,
            ax0.y * i0 + ax1.y * i1 + ax2.y * i2);
    if (lane < 16)
      aggr_u[(size_t)n0 * 80 + 64 + lane] =
          pk2(ae0.x * i0 + ae1.x * i1 + ae2.x * i2,
              ae0.y * i0 + ae1.y * i1 + ae2.y * i2);
  }
}

// ------------------------------------------------------------------
// final layer: out = aggr @ euw + bias via MFMA, store d_out in
// detected dtype. Grid (N/16, 2), 4 waves/block.
// ------------------------------------------------------------------
__global__ __launch_bounds__(256) void gemm_out_mfma(
    const bf16* __restrict__ aggr, const bf16* __restrict__ euwT,
    const float* __restrict__ biasf, void* __restrict__ dout,
    const int* __restrict__ flag, int N) {
  int wave = threadIdx.x >> 6, lane = threadIdx.x & 63;
  int row_base = blockIdx.x * 16;
  int col_base = blockIdx.y * 64 + wave * 16;
  int quad = lane >> 4, r16 = lane & 15;
  int row = row_base + r16; if (row >= N) row = N - 1;
  int col = col_base + r16;
  f32x4 acc = {0.f, 0.f, 0.f, 0.f};
  const short8* ap = (const short8*)(aggr + (size_t)row * 160 + quad * 8);
  const short8* bp = (const short8*)(euwT + (size_t)col * 160 + quad * 8);
#pragma unroll
  for (int kk = 0; kk < 5; ++kk) {
    short8 a = ap[kk * 4];
    short8 b = bp[kk * 4];
    acc = __builtin_amdgcn_mfma_f32_16x16x32_bf16(a, b, acc, 0, 0, 0);
  }
  float bv = biasf[col];
  int f = *flag;
#pragma unroll
  for (int r = 0; r < 4; ++r) {
    int node = row_base + quad * 4 + r;
    if (node < N) {
      float v = acc[r] + bv;
      if (f) ((float*)dout)[(size_t)node * 128 + col] = v;
      else   ((bf16*)dout)[(size_t)node * 128 + col] = __float2bfloat16(v);
    }
  }
}

// ------------------------------------------------------------------
extern "C" void kernel_launch(void* const* d_in, const int* in_sizes, int n_in,
                              void* d_out, int out_size, void* d_ws, size_t ws_size,
                              hipStream_t stream) {
  const int* x_idx = (const int*)d_in[0];
  const int* edge_index = (const int*)d_in[1];
  const int* edge_attr_idx = (const int*)d_in[2];

  int N = in_sizes[0];
  int E0 = in_sizes[1] / 2;
  int E = E0 + N;
  const int* src = edge_index;
  const int* dst = edge_index + E0;

  // ---- workspace carve (~12.2 MB) ----
  size_t off = 0;
  char* base = (char*)d_ws;
  auto carve = [&](size_t bytes) -> void* {
    void* p = base + off;
    off += (bytes + 255) & ~(size_t)255;
    return p;
  };
  int* flag     = (int*)carve(256);
  int* counts   = (int*)carve((size_t)N * 4);    // becomes cursor after scan
  int* row_ptr  = (int*)carve((size_t)(N + 1) * 4);
  int* packed   = (int*)carve((size_t)E * 4);
  float* s_i    = (float*)carve((size_t)N * 3 * 4);
  float* s_j    = (float*)carve((size_t)N * 3 * 4 + 16);  // +16: dwordx4 overread
  float* s_et   = (float*)carve(2 * 65 * 3 * 4);
  float* eef    = (float*)carve(2048 * 4);
  float* att1f  = (float*)carve(864 * 4);
  float* att2f  = (float*)carve(864 * 4);
  float* b1f    = (float*)carve(128 * 4);
  float* b2f_   = (float*)carve(128 * 4);
  bf16* WT1     = (bf16*)carve(49152 * 2);
  bf16* WT2     = (bf16*)carve(49152 * 2);
  bf16* euT1    = (bf16*)carve(20480 * 2);
  bf16* euT2    = (bf16*)carve(20480 * 2);
  bf16* xh      = (bf16*)carve((size_t)N * 384 * 2 + 64);
  bf16* aggr    = (bf16*)carve((size_t)N * 160 * 2);
  bf16* xb      = (bf16*)d_out;  // bf16 x0 lives in d_out
  (void)n_in; (void)out_size; (void)ws_size;

  // ---- setup: 4 dispatches ----
  wconv_kernel<<<(143296 + N + 255) / 256, 256, 0, stream>>>(
      d_in[4], d_in[5], d_in[6], d_in[7], d_in[8], d_in[9], d_in[10], d_in[11],
      d_in[12], flag, eef, att1f, att2f, b1f, b2f_, WT1, WT2, euT1, euT2,
      s_et, counts, N);
  int nb4 = (N + 3) / 4;
  prep_kernel<<<nb4, 256, 0, stream>>>(x_idx, d_in[3], flag, xb, counts, dst,
                                       E0, N);
  scan_kernel<<<1, 1024, 0, stream>>>(counts, row_ptr, N);
  scatter_kernel<<<(E + 255) / 256, 256, 0, stream>>>(src, dst, edge_attr_idx,
                                                      counts, packed, E0, N);

  int nrb16 = (N + 15) / 16;
  int nrb32 = (N + 31) / 32;
  int nb2 = (N + 1) / 2;

  // layer (0,0): W1/att1
  gemm_xh_s_mfma<<<nrb32, 384, 0, stream>>>(xb, WT1, att1f, xh, s_i, s_j, N);
  edge_aggr_kernel<<<nb2, 256, 0, stream>>>(
      (const int*)xh, s_i, s_j, s_et, (const float2*)eef,
      row_ptr, packed, (unsigned*)aggr, N, E);
  // boundary (0,0)->(0,1): euw1+b1+ELU, then W2/att2
  fox_kernel<<<nrb16, 384, 0, stream>>>(aggr, euT1, b1f, 1, WT2, att2f,
                                        xh, s_i, s_j, N);
  edge_aggr_kernel<<<nb2, 256, 0, stream>>>(
      (const int*)xh, s_i, s_j, s_et + 195, (const float2*)eef,
      row_ptr, packed, (unsigned*)aggr, N, E);
  // boundary (0,1)->(1,0): euw2+b2 (no ELU), then W1/att1
  fox_kernel<<<nrb16, 384, 0, stream>>>(aggr, euT2, b2f_, 0, WT1, att1f,
                                        xh, s_i, s_j, N);
  edge_aggr_kernel<<<nb2, 256, 0, stream>>>(
      (const int*)xh, s_i, s_j, s_et, (const float2*)eef,
      row_ptr, packed, (unsigned*)aggr, N, E);
  // boundary (1,0)->(1,1): euw1+b1+ELU, then W2/att2
  fox_kernel<<<nrb16, 384, 0, stream>>>(aggr, euT1, b1f, 1, WT2, att2f,
                                        xh, s_i, s_j, N);
  edge_aggr_kernel<<<nb2, 256, 0, stream>>>(
      (const int*)xh, s_i, s_j, s_et + 195, (const float2*)eef,
      row_ptr, packed, (unsigned*)aggr, N, E);
  // final: euw2+b2, store d_out
  gemm_out_mfma<<<dim3(nrb16, 2), 256, 0, stream>>>(aggr, euT2, b2f_,
                                                    d_out, flag, N);
}

// Round 5
// 316.146 us; speedup vs baseline: 1.0843x; 1.0843x over previous
//
#include <hip/hip_runtime.h>
#include <hip/hip_bf16.h>

typedef __hip_bfloat16 bf16;
typedef __attribute__((ext_vector_type(8))) short short8;
typedef __attribute__((ext_vector_type(4))) float f32x4;
typedef __attribute__((ext_vector_type(3), aligned(4))) int i32x3u;
typedef __attribute__((ext_vector_type(4))) int i32x4;

__device__ __forceinline__ float b2f(bf16 v) { return __bfloat162float(v); }
// int (2 packed bf16) -> two floats. x = low half, y = high half.
__device__ __forceinline__ float2 i2f2(int w) {
  float lo = __uint_as_float(((unsigned)w) << 16);
  float hi = __uint_as_float(((unsigned)w) & 0xFFFF0000u);
  return make_float2(lo, hi);
}
// float -> bf16 bits (RNE; inputs finite)
__device__ __forceinline__ unsigned f2bfb(float f) {
  unsigned u = __float_as_uint(f);
  unsigned r = 0x7FFFu + ((u >> 16) & 1u);
  return (u + r) >> 16;
}
__device__ __forceinline__ unsigned pk2(float a, float b) {
  return f2bfb(a) | (f2bfb(b) << 16);
}
__device__ __forceinline__ float ldv(const void* p, int i, int f) {
  return f ? ((const float*)p)[i] : b2f(((const bf16*)p)[i]);
}

#define SH 392  // stage row stride in halfs (384 + 8 pad, 16B-aligned)

// ------------------------------------------------------------------
// weight materialization + per-block dtype detect + counts zero;
// block 0 computes s_et and publishes flag.
// ------------------------------------------------------------------
__global__ __launch_bounds__(256) void wconv_kernel(
    const void* __restrict__ ee, const void* __restrict__ w1,
    const void* __restrict__ a1, const void* __restrict__ eu1,
    const void* __restrict__ b1, const void* __restrict__ w2,
    const void* __restrict__ a2, const void* __restrict__ eu2,
    const void* __restrict__ b2, int* __restrict__ flag,
    float* __restrict__ eef, float* __restrict__ att1f, float* __restrict__ att2f,
    float* __restrict__ b1f, float* __restrict__ b2f,
    bf16* __restrict__ WT1, bf16* __restrict__ WT2,
    bf16* __restrict__ euT1, bf16* __restrict__ euT2,
    float* __restrict__ s_et, int* __restrict__ counts, int N) {
  __shared__ int cnt;
  __shared__ int fl;
  if (threadIdx.x == 0) cnt = 0;
  __syncthreads();
  const unsigned short* probe = (const unsigned short*)w1;
  int local = 0;
#pragma unroll
  for (int k = 0; k < 8; ++k) {
    int e = (probe[threadIdx.x * 8 + k] >> 7) & 0xFF;
    if (e >= 160) local++;
  }
  if (local) atomicAdd(&cnt, local);
  __syncthreads();
  if (threadIdx.x == 0) {
    fl = (cnt > 16) ? 1 : 0;
    if (blockIdx.x == 0) *flag = fl;
  }
  __syncthreads();
  int f = fl;

  int i = blockIdx.x * 256 + threadIdx.x;
  if (i < 2048) {
    eef[i] = ldv(ee, i, f);
  } else if (i < 2912) {
    att1f[i - 2048] = ldv(a1, i - 2048, f);
  } else if (i < 3776) {
    att2f[i - 2912] = ldv(a2, i - 2912, f);
  } else if (i < 3904) {
    b1f[i - 3776] = ldv(b1, i - 3776, f);
  } else if (i < 4032) {
    b2f[i - 3904] = ldv(b2, i - 3904, f);
  } else if (i < 53184) {
    int j = i - 4032; int c = j >> 7, k = j & 127;
    WT1[j] = __float2bfloat16(ldv(w1, k * 384 + c, f));
  } else if (i < 102336) {
    int j = i - 53184; int c = j >> 7, k = j & 127;
    WT2[j] = __float2bfloat16(ldv(w2, k * 384 + c, f));
  } else if (i < 122816) {
    int j = i - 102336; int c = j / 160, k = j % 160;
    euT1[j] = __float2bfloat16(ldv(eu1, k * 128 + c, f));
  } else if (i < 143296) {
    int j = i - 122816; int c = j / 160, k = j % 160;
    euT2[j] = __float2bfloat16(ldv(eu2, k * 128 + c, f));
  } else if (i < 143296 + N) {
    counts[i - 143296] = 0;
  }

  if (blockIdx.x == 0) {
    for (int id = threadIdx.x; id < 2 * 65 * 3; id += 256) {
      int l = id / (65 * 3);
      int r = id % (65 * 3);
      int t = r / 3, h = r % 3;
      const void* att = l ? a2 : a1;
      float s = 0.0f;
      if (t < 64) {
        for (int d = 0; d < 32; ++d)
          s += ldv(ee, t * 32 + d, f) * ldv(att, h * 288 + 256 + d, f);
      }
      s_et[id] = s;
    }
  }
}

// ------------------------------------------------------------------
// prep: x0 = maxnorm(node_emb[x_idx]) -> bf16 x (in d_out);
// + edge counting (grid-stride). counts pre-zeroed by wconv.
// ------------------------------------------------------------------
__global__ __launch_bounds__(256) void prep_kernel(
    const int* __restrict__ x_idx, const void* __restrict__ node_emb,
    const int* __restrict__ flag, bf16* __restrict__ xb,
    int* __restrict__ counts, const int* __restrict__ dst, int E0, int N) {
  int wid = threadIdx.x >> 6, lane = threadIdx.x & 63;
  int n = blockIdx.x * 4 + wid;
  if (n < N) {
    int idx = x_idx[n];
    if ((unsigned)idx >= (unsigned)N) idx = 0;
    float v0, v1;
    if (*flag) {
      const float* er = (const float*)node_emb + (size_t)idx * 128;
      v0 = er[lane]; v1 = er[lane + 64];
    } else {
      const bf16* er = (const bf16*)node_emb + (size_t)idx * 128;
      v0 = b2f(er[lane]); v1 = b2f(er[lane + 64]);
    }
    float ss = v0 * v0 + v1 * v1;
#pragma unroll
    for (int d = 32; d > 0; d >>= 1) ss += __shfl_xor(ss, d);
    float norm = sqrtf(ss);
    float scale = norm > 1.0f ? 1.0f / norm : 1.0f;
    xb[(size_t)n * 128 + lane] = __float2bfloat16(v0 * scale);
    xb[(size_t)n * 128 + 64 + lane] = __float2bfloat16(v1 * scale);
  }
  int gid = blockIdx.x * 256 + threadIdx.x;
  int stride = gridDim.x * 256;
  for (int i = gid; i < E0; i += stride) {
    int d = dst[i];
    if ((unsigned)d >= (unsigned)N) d = 0;
    atomicAdd(&counts[d], 1);
  }
}

// ------------------------------------------------------------------
// parallel exclusive scan with +1 per row (self loop), one block of
// 1024 threads (16 waves). counts becomes cursor in place.
// ------------------------------------------------------------------
__global__ __launch_bounds__(1024) void scan_kernel(
    int* __restrict__ counts, int* __restrict__ row_ptr, int N) {
  __shared__ int wsum[16];
  int t = threadIdx.x;
  int chunk = (N + 1023) >> 10;
  int lo = t * chunk;
  int hi = lo + chunk;
  if (lo > N) lo = N;
  if (hi > N) hi = N;
  int s = 0;
  for (int i = lo; i < hi; ++i) s += counts[i] + 1;
  int lane = t & 63, wv = t >> 6;
  int incl = s;
#pragma unroll
  for (int d = 1; d < 64; d <<= 1) {
    int u = __shfl_up(incl, d);
    if (lane >= d) incl += u;
  }
  if (lane == 63) wsum[wv] = incl;
  __syncthreads();
  if (t == 0) {
    int run = 0;
#pragma unroll
    for (int w = 0; w < 16; ++w) { int c = wsum[w]; wsum[w] = run; run += c; }
  }
  __syncthreads();
  int run = incl - s + wsum[wv];  // exclusive prefix for this thread
  for (int i = lo; i < hi; ++i) {
    int c = counts[i] + 1;
    row_ptr[i] = run;
    counts[i] = run;
    run += c;
  }
  if (t == 1023) row_ptr[N] = run;
}

// ------------------------------------------------------------------
// scatter edges (+self loops, etype=64) into CSR: packed = src | et<<16
// ------------------------------------------------------------------
__global__ __launch_bounds__(256) void scatter_kernel(
    const int* __restrict__ src, const int* __restrict__ dst,
    const int* __restrict__ et, int* __restrict__ cursor,
    int* __restrict__ packed, int E0, int N) {
  int E = E0 + N;
  int i = blockIdx.x * blockDim.x + threadIdx.x;
  if (i < E0) {
    int d = dst[i];
    if ((unsigned)d >= (unsigned)N) d = 0;
    int p = atomicAdd(&cursor[d], 1);
    if ((unsigned)p >= (unsigned)E) p = 0;
    int t = et[i] & 63;
    packed[p] = (src[i] & 0xFFFF) | (t << 16);
  } else if (i < E) {
    int n = i - E0;
    int p = atomicAdd(&cursor[n], 1);
    if ((unsigned)p >= (unsigned)E) p = 0;
    packed[p] = (n & 0xFFFF) | (64 << 16);
  }
}

// ------------------------------------------------------------------
// xh = x @ W via MFMA + fused s_i/s_j (layer 0; x = bf16 in d_out).
// Block = 6 waves (384 thr), 32 rows x 384 cols. Grid: N/32.
// xh permuted (half-index = node*384 + pair*6 + head*2 + sub) staged
// in LDS, written out as contiguous 16B chunks.
// ------------------------------------------------------------------
__global__ __launch_bounds__(384) void gemm_xh_s_mfma(
    const bf16* __restrict__ x, const bf16* __restrict__ WT,
    const float* __restrict__ attf, bf16* __restrict__ xh,
    float* __restrict__ s_i, float* __restrict__ s_j, int N) {
  __shared__ __align__(16) bf16 stage[32 * SH];
  __shared__ float lds_i[6][32];
  __shared__ float lds_j[6][32];
  int wave = threadIdx.x >> 6, lane = threadIdx.x & 63;
  int row_base = blockIdx.x * 32;
  int quad = lane >> 4, r16 = lane & 15;
  int rowA = row_base + r16;      if (rowA >= N) rowA = N - 1;
  int rowB = row_base + 16 + r16; if (rowB >= N) rowB = N - 1;
  const short8* apA = (const short8*)(x + (size_t)rowA * 128 + quad * 8);
  const short8* apB = (const short8*)(x + (size_t)rowB * 128 + quad * 8);
  short8 aA[4], aB[4];
#pragma unroll
  for (int kk = 0; kk < 4; ++kk) { aA[kk] = apA[kk * 4]; aB[kk] = apB[kk * 4]; }

  float piA[4] = {0.f, 0.f, 0.f, 0.f}, pjA[4] = {0.f, 0.f, 0.f, 0.f};
  float piB[4] = {0.f, 0.f, 0.f, 0.f}, pjB[4] = {0.f, 0.f, 0.f, 0.f};
#pragma unroll
  for (int j = 0; j < 4; ++j) {
    int col = wave * 64 + j * 16 + r16;
    const short8* bp = (const short8*)(WT + (size_t)col * 128 + quad * 8);
    short8 b[4];
#pragma unroll
    for (int kk = 0; kk < 4; ++kk) b[kk] = bp[kk * 4];
    f32x4 accA = {0.f, 0.f, 0.f, 0.f};
    f32x4 accB = {0.f, 0.f, 0.f, 0.f};
#pragma unroll
    for (int kk = 0; kk < 4; ++kk) {
      accA = __builtin_amdgcn_mfma_f32_16x16x32_bf16(aA[kk], b[kk], accA, 0, 0, 0);
      accB = __builtin_amdgcn_mfma_f32_16x16x32_bf16(aB[kk], b[kk], accB, 0, 0, 0);
    }
    int h = col >> 7, fi = col & 127, pair = fi >> 1, sub = fi & 1;
    int base = pair * 6 + h * 2 + sub;
#pragma unroll
    for (int r = 0; r < 4; ++r) {
      stage[(quad * 4 + r) * SH + base] = __float2bfloat16(accA[r]);
      stage[(16 + quad * 4 + r) * SH + base] = __float2bfloat16(accB[r]);
    }
    float ai = attf[h * 288 + fi];
    float aj = attf[h * 288 + 128 + fi];
#pragma unroll
    for (int r = 0; r < 4; ++r) {
      piA[r] = fmaf(accA[r], ai, piA[r]);
      pjA[r] = fmaf(accA[r], aj, pjA[r]);
      piB[r] = fmaf(accB[r], ai, piB[r]);
      pjB[r] = fmaf(accB[r], aj, pjB[r]);
    }
  }
#pragma unroll
  for (int d = 1; d < 16; d <<= 1) {
#pragma unroll
    for (int r = 0; r < 4; ++r) {
      piA[r] += __shfl_xor(piA[r], d);
      pjA[r] += __shfl_xor(pjA[r], d);
      piB[r] += __shfl_xor(piB[r], d);
      pjB[r] += __shfl_xor(pjB[r], d);
    }
  }
  if (r16 == 0) {
#pragma unroll
    for (int r = 0; r < 4; ++r) {
      lds_i[wave][quad * 4 + r] = piA[r];
      lds_j[wave][quad * 4 + r] = pjA[r];
      lds_i[wave][16 + quad * 4 + r] = piB[r];
      lds_j[wave][16 + quad * 4 + r] = pjB[r];
    }
  }
  __syncthreads();
  int m = threadIdx.x;
  if (m < 96) {
    int h = m / 32, r = m % 32;
    int node = row_base + r;
    if (node < N) s_i[node * 3 + h] = lds_i[2 * h][r] + lds_i[2 * h + 1][r];
  } else if (m < 192) {
    int tt = m - 96;
    int h = tt / 32, r = tt % 32;
    int node = row_base + r;
    if (node < N) s_j[node * 3 + h] = lds_j[2 * h][r] + lds_j[2 * h + 1][r];
  }
  // contiguous copy-out: 32 rows x 48 chunks of 16B
#pragma unroll
  for (int k = 0; k < 4; ++k) {
    int c = threadIdx.x + k * 384;
    int r = c / 48, o = c % 48;
    int node = row_base + r;
    if (node < N)
      *(i32x4*)(xh + (size_t)node * 384 + o * 8) =
          *(const i32x4*)(stage + r * SH + o * 8);
  }
}

// ------------------------------------------------------------------
// FOX: fused layer boundary. Phase 1: out = aggr @ euw + bias (+ELU),
// 16x128 bf16 tile in LDS. Phase 2: xh' = out @ W via MFMA (A from
// LDS) + fused s_i/s_j; xh' staged in LDS, contiguous copy-out.
// Grid N/16, 384 threads.
// ------------------------------------------------------------------
__global__ __launch_bounds__(384) void fox_kernel(
    const bf16* __restrict__ aggr, const bf16* __restrict__ euwT,
    const float* __restrict__ biasf, int do_elu,
    const bf16* __restrict__ WT, const float* __restrict__ attf,
    bf16* __restrict__ xh, float* __restrict__ s_i, float* __restrict__ s_j,
    int N) {
  __shared__ bf16 xtile[16][136];  // [m][k], row stride 272 B
  __shared__ __align__(16) bf16 stage[16 * SH];
  __shared__ float lds_i[6][16];
  __shared__ float lds_j[6][16];
  int wave = threadIdx.x >> 6, lane = threadIdx.x & 63;
  int quad = lane >> 4, r16 = lane & 15;
  int row_base = blockIdx.x * 16;
  int row = row_base + r16; if (row >= N) row = N - 1;

  // ---- phase 1: out tile (K=160) ----
  const short8* ap = (const short8*)(aggr + (size_t)row * 160 + quad * 8);
  short8 aa[5];
#pragma unroll
  for (int kk = 0; kk < 5; ++kk) aa[kk] = ap[kk * 4];
  for (int t = wave; t < 8; t += 6) {
    int col = t * 16 + r16;
    const short8* bp = (const short8*)(euwT + (size_t)col * 160 + quad * 8);
    f32x4 acc = {0.f, 0.f, 0.f, 0.f};
#pragma unroll
    for (int kk = 0; kk < 5; ++kk)
      acc = __builtin_amdgcn_mfma_f32_16x16x32_bf16(aa[kk], bp[kk * 4], acc, 0, 0, 0);
    float bv = biasf[col];
#pragma unroll
    for (int r = 0; r < 4; ++r) {
      float v = acc[r] + bv;
      if (do_elu) v = v > 0.0f ? v : expm1f(v);
      xtile[quad * 4 + r][col] = __float2bfloat16(v);
    }
  }
  __syncthreads();

  // ---- phase 2: xh' = xtile @ W (K=128), A from LDS ----
  short8 a[4];
#pragma unroll
  for (int kk = 0; kk < 4; ++kk)
    a[kk] = *(const short8*)(&xtile[r16][quad * 8 + kk * 32]);

  float pi_r[4] = {0.f, 0.f, 0.f, 0.f};
  float pj_r[4] = {0.f, 0.f, 0.f, 0.f};
#pragma unroll
  for (int j = 0; j < 4; ++j) {
    int col = wave * 64 + j * 16 + r16;
    const short8* bp = (const short8*)(WT + (size_t)col * 128 + quad * 8);
    f32x4 acc = {0.f, 0.f, 0.f, 0.f};
#pragma unroll
    for (int kk = 0; kk < 4; ++kk)
      acc = __builtin_amdgcn_mfma_f32_16x16x32_bf16(a[kk], bp[kk * 4], acc, 0, 0, 0);
    int h = col >> 7, fi = col & 127, pair = fi >> 1, sub = fi & 1;
    int base = pair * 6 + h * 2 + sub;
#pragma unroll
    for (int r = 0; r < 4; ++r)
      stage[(quad * 4 + r) * SH + base] = __float2bfloat16(acc[r]);
    float ai = attf[h * 288 + fi];
    float aj = attf[h * 288 + 128 + fi];
#pragma unroll
    for (int r = 0; r < 4; ++r) {
      pi_r[r] = fmaf(acc[r], ai, pi_r[r]);
      pj_r[r] = fmaf(acc[r], aj, pj_r[r]);
    }
  }
#pragma unroll
  for (int d = 1; d < 16; d <<= 1) {
#pragma unroll
    for (int r = 0; r < 4; ++r) {
      pi_r[r] += __shfl_xor(pi_r[r], d);
      pj_r[r] += __shfl_xor(pj_r[r], d);
    }
  }
  if (r16 == 0) {
#pragma unroll
    for (int r = 0; r < 4; ++r) {
      lds_i[wave][quad * 4 + r] = pi_r[r];
      lds_j[wave][quad * 4 + r] = pj_r[r];
    }
  }
  __syncthreads();
  int m = threadIdx.x;
  if (m < 48) {
    int h = m / 16, r = m % 16;
    int node = row_base + r;
    if (node < N) s_i[node * 3 + h] = lds_i[2 * h][r] + lds_i[2 * h + 1][r];
  } else if (m < 96) {
    int tt = m - 48;
    int h = tt / 16, r = tt % 16;
    int node = row_base + r;
    if (node < N) s_j[node * 3 + h] = lds_j[2 * h][r] + lds_j[2 * h + 1][r];
  }
  // contiguous copy-out: 16 rows x 48 chunks of 16B
#pragma unroll
  for (int k = 0; k < 2; ++k) {
    int c = threadIdx.x + k * 384;
    int r = c / 48, o = c % 48;
    int node = row_base + r;
    if (node < N)
      *(i32x4*)(xh + (size_t)node * 384 + o * 8) =
          *(const i32x4*)(stage + r * SH + o * 8);
  }
}

// ------------------------------------------------------------------
// per-dst softmax + weighted aggregation -> bf16 aggr [N][160].
// 2 waves per node; partials combined via LDS. Per-edge gather is an
// exact 12B dwordx3 per lane (no row-straddle).
// ------------------------------------------------------------------
__global__ __launch_bounds__(256) void edge_aggr_kernel(
    const int* __restrict__ xh_i, const float* __restrict__ s_i,
    const float* __restrict__ s_j, const float* __restrict__ s_et,
    const float2* __restrict__ eef2, const int* __restrict__ row_ptr,
    const int* __restrict__ packed, unsigned* __restrict__ aggr_u,
    int N, int E) {
  __shared__ float lds[2][512];
  int wid = threadIdx.x >> 6, lane = threadIdx.x & 63;
  int nodeLocal = wid >> 1, w = wid & 1;
  int n0 = blockIdx.x * 2 + nodeLocal;
  int n = n0 < N ? n0 : N - 1;
  int start = row_ptr[n], end = row_ptr[n + 1];
  if (start < 0) start = 0;
  if (start > E) start = E;
  if (end < start) end = start;
  if (end > E) end = E;
  int deg = end - start;
  float si0 = s_i[n * 3 + 0], si1 = s_i[n * 3 + 1], si2 = s_i[n * 3 + 2];

  float p0r = 0.f, p1r = 0.f, p2r = 0.f;
  int pkr = 0;
  float dp0 = 0.0f, dp1 = 0.0f, dp2 = 0.0f;
  int slot = 2 * lane + w;
  if (slot < deg) {
    int p = packed[start + slot];
    int s = p & 0xFFFF; if (s >= N) s = N - 1;
    int t = (p >> 16) & 127; if (t > 64) t = 64;
    float a0 = si0 + s_j[s * 3 + 0] + s_et[t * 3 + 0];
    float a1 = si1 + s_j[s * 3 + 1] + s_et[t * 3 + 1];
    float a2 = si2 + s_j[s * 3 + 2] + s_et[t * 3 + 2];
    a0 = a0 > 0.0f ? a0 : 0.2f * a0;
    a1 = a1 > 0.0f ? a1 : 0.2f * a1;
    a2 = a2 > 0.0f ? a2 : 0.2f * a2;
    a0 = fminf(fmaxf(a0, -60.0f), 60.0f);
    a1 = fminf(fmaxf(a1, -60.0f), 60.0f);
    a2 = fminf(fmaxf(a2, -60.0f), 60.0f);
    p0r = __expf(a0); p1r = __expf(a1); p2r = __expf(a2);
    dp0 = p0r; dp1 = p1r; dp2 = p2r;
    pkr = s | (t << 16);
  }
#pragma unroll
  for (int d = 32; d > 0; d >>= 1) {
    dp0 += __shfl_xor(dp0, d);
    dp1 += __shfl_xor(dp1, d);
    dp2 += __shfl_xor(dp2, d);
  }
  float d0 = dp0, d1 = dp1, d2 = dp2;

  float2 ax0 = make_float2(0.f, 0.f), ax1 = ax0, ax2 = ax0;
  float2 ae0 = ax0, ae1 = ax0, ae2 = ax0;
  int capped = deg < 128 ? deg : 128;
  int cnt = (capped > w) ? ((capped - w + 1) >> 1) : 0;

  {
    int j = 0;
    for (; j + 2 <= cnt; j += 2) {
      int pkA = __shfl(pkr, j), pkB = __shfl(pkr, j + 1);
      float qA0 = __shfl(p0r, j), qB0 = __shfl(p0r, j + 1);
      float qA1 = __shfl(p1r, j), qB1 = __shfl(p1r, j + 1);
      float qA2 = __shfl(p2r, j), qB2 = __shfl(p2r, j + 1);
      int sA = pkA & 0xFFFF, tA = pkA >> 16;
      int sB = pkB & 0xFFFF, tB = pkB >> 16;
      i32x3u qA = *(const i32x3u*)(xh_i + (size_t)sA * 192 + lane * 3);
      i32x3u qB = *(const i32x3u*)(xh_i + (size_t)sB * 192 + lane * 3);
      float2 vA0 = i2f2(qA.x), vA1 = i2f2(qA.y), vA2 = i2f2(qA.z);
      float2 vB0 = i2f2(qB.x), vB1 = i2f2(qB.y), vB2 = i2f2(qB.z);
      ax0.x = fmaf(qA0, vA0.x, ax0.x); ax0.y = fmaf(qA0, vA0.y, ax0.y);
      ax1.x = fmaf(qA1, vA1.x, ax1.x); ax1.y = fmaf(qA1, vA1.y, ax1.y);
      ax2.x = fmaf(qA2, vA2.x, ax2.x); ax2.y = fmaf(qA2, vA2.y, ax2.y);
      ax0.x = fmaf(qB0, vB0.x, ax0.x); ax0.y = fmaf(qB0, vB0.y, ax0.y);
      ax1.x = fmaf(qB1, vB1.x, ax1.x); ax1.y = fmaf(qB1, vB1.y, ax1.y);
      ax2.x = fmaf(qB2, vB2.x, ax2.x); ax2.y = fmaf(qB2, vB2.y, ax2.y);
      if (lane < 16) {
        if (tA != 64) {
          float2 ev = eef2[tA * 16 + lane];
          ae0.x = fmaf(qA0, ev.x, ae0.x); ae0.y = fmaf(qA0, ev.y, ae0.y);
          ae1.x = fmaf(qA1, ev.x, ae1.x); ae1.y = fmaf(qA1, ev.y, ae1.y);
          ae2.x = fmaf(qA2, ev.x, ae2.x); ae2.y = fmaf(qA2, ev.y, ae2.y);
        }
        if (tB != 64) {
          float2 ev = eef2[tB * 16 + lane];
          ae0.x = fmaf(qB0, ev.x, ae0.x); ae0.y = fmaf(qB0, ev.y, ae0.y);
          ae1.x = fmaf(qB1, ev.x, ae1.x); ae1.y = fmaf(qB1, ev.y, ae1.y);
          ae2.x = fmaf(qB2, ev.x, ae2.x); ae2.y = fmaf(qB2, ev.y, ae2.y);
        }
      }
    }
    if (j < cnt) {
      int pkA = __shfl(pkr, j);
      float qA0 = __shfl(p0r, j), qA1 = __shfl(p1r, j), qA2 = __shfl(p2r, j);
      int sA = pkA & 0xFFFF, tA = pkA >> 16;
      i32x3u qA = *(const i32x3u*)(xh_i + (size_t)sA * 192 + lane * 3);
      float2 vA0 = i2f2(qA.x), vA1 = i2f2(qA.y), vA2 = i2f2(qA.z);
      ax0.x = fmaf(qA0, vA0.x, ax0.x); ax0.y = fmaf(qA0, vA0.y, ax0.y);
      ax1.x = fmaf(qA1, vA1.x, ax1.x); ax1.y = fmaf(qA1, vA1.y, ax1.y);
      ax2.x = fmaf(qA2, vA2.x, ax2.x); ax2.y = fmaf(qA2, vA2.y, ax2.y);
      if (lane < 16 && tA != 64) {
        float2 ev = eef2[tA * 16 + lane];
        ae0.x = fmaf(qA0, ev.x, ae0.x); ae0.y = fmaf(qA0, ev.y, ae0.y);
        ae1.x = fmaf(qA1, ev.x, ae1.x); ae1.y = fmaf(qA1, ev.y, ae1.y);
        ae2.x = fmaf(qA2, ev.x, ae2.x); ae2.y = fmaf(qA2, ev.y, ae2.y);
      }
    }
  }

  if (w == 0) {
    for (int e = start + 128; e < end; ++e) {
      int p = packed[e];
      int s = p & 0xFFFF; if (s >= N) s = N - 1;
      int t = (p >> 16) & 127; if (t > 64) t = 64;
      float a0 = si0 + s_j[s * 3 + 0] + s_et[t * 3 + 0];
      float a1 = si1 + s_j[s * 3 + 1] + s_et[t * 3 + 1];
      float a2 = si2 + s_j[s * 3 + 2] + s_et[t * 3 + 2];
      a0 = a0 > 0.0f ? a0 : 0.2f * a0;
      a1 = a1 > 0.0f ? a1 : 0.2f * a1;
      a2 = a2 > 0.0f ? a2 : 0.2f * a2;
      a0 = fminf(fmaxf(a0, -60.0f), 60.0f);
      a1 = fminf(fmaxf(a1, -60.0f), 60.0f);
      a2 = fminf(fmaxf(a2, -60.0f), 60.0f);
      float p0 = __expf(a0), p1 = __expf(a1), p2 = __expf(a2);
      d0 += p0; d1 += p1; d2 += p2;
      i32x3u q = *(const i32x3u*)(xh_i + (size_t)s * 192 + lane * 3);
      float2 v0 = i2f2(q.x), v1 = i2f2(q.y), v2 = i2f2(q.z);
      ax0.x = fmaf(p0, v0.x, ax0.x); ax0.y = fmaf(p0, v0.y, ax0.y);
      ax1.x = fmaf(p1, v1.x, ax1.x); ax1.y = fmaf(p1, v1.y, ax1.y);
      ax2.x = fmaf(p2, v2.x, ax2.x); ax2.y = fmaf(p2, v2.y, ax2.y);
      if (t != 64 && lane < 16) {
        float2 ev = eef2[t * 16 + lane];
        ae0.x = fmaf(p0, ev.x, ae0.x); ae0.y = fmaf(p0, ev.y, ae0.y);
        ae1.x = fmaf(p1, ev.x, ae1.x); ae1.y = fmaf(p1, ev.y, ae1.y);
        ae2.x = fmaf(p2, ev.x, ae2.x); ae2.y = fmaf(p2, ev.y, ae2.y);
      }
    }
  }

  float* L = lds[nodeLocal];
  if (w == 1) {
    L[lane * 2 + 0] = ax0.x;       L[lane * 2 + 1] = ax0.y;
    L[128 + lane * 2 + 0] = ax1.x; L[128 + lane * 2 + 1] = ax1.y;
    L[256 + lane * 2 + 0] = ax2.x; L[256 + lane * 2 + 1] = ax2.y;
    if (lane < 16) {
      L[384 + lane * 2 + 0] = ae0.x; L[384 + lane * 2 + 1] = ae0.y;
      L[416 + lane * 2 + 0] = ae1.x; L[416 + lane * 2 + 1] = ae1.y;
      L[448 + lane * 2 + 0] = ae2.x; L[448 + lane * 2 + 1] = ae2.y;
    }
    if (lane == 0) { L[480] = d0; L[481] = d1; L[482] = d2; }
  }
  __syncthreads();
  if (w == 0 && n0 < N) {
    ax0.x += L[lane * 2 + 0];       ax0.y += L[lane * 2 + 1];
    ax1.x += L[128 + lane * 2 + 0]; ax1.y += L[128 + lane * 2 + 1];
    ax2.x += L[256 + lane * 2 + 0]; ax2.y += L[256 + lane * 2 + 1];
    if (lane < 16) {
      ae0.x += L[384 + lane * 2 + 0]; ae0.y += L[384 + lane * 2 + 1];
      ae1.x += L[416 + lane * 2 + 0]; ae1.y += L[416 + lane * 2 + 1];
      ae2.x += L[448 + lane * 2 + 0]; ae2.y += L[448 + lane * 2 + 1];
    }
    d0 += L[480]; d1 += L[481]; d2 += L[482];
    const float third = 1.0f / 3.0f;
    float i0 = third / fmaxf(d0, 1e-30f);
    float i1 = third / fmaxf(d1, 1e-30f);
    float i2 = third / fmaxf(d2, 1e-30f);
    aggr_u[(size_t)n0 * 80 + lane] =
        pk2(ax0.x * i0 + ax1.x * i1 + ax2.x * i2,
            ax0.y * i0 + ax1.y * i1 + ax2.y * i2);
    if (lane < 16)
      aggr_u[(size_t)n0 * 80 + 64 + lane] =
          pk2(ae0.x * i0 + ae1.x * i1 + ae2.x * i2,
              ae0.y * i0 + ae1.y * i1 + ae2.y * i2);
  }
}

// ------------------------------------------------------------------
// final layer: out = aggr @ euw + bias via MFMA, store d_out in
// detected dtype. Grid (N/16, 2), 4 waves/block.
// ------------------------------------------------------------------
__global__ __launch_bounds__(256) void gemm_out_mfma(
    const bf16* __restrict__ aggr, const bf16* __restrict__ euwT,
    const float* __restrict__ biasf, void* __restrict__ dout,
    const int* __restrict__ flag, int N) {
  int wave = threadIdx.x >> 6, lane = threadIdx.x & 63;
  int row_base = blockIdx.x * 16;
  int col_base = blockIdx.y * 64 + wave * 16;
  int quad = lane >> 4, r16 = lane & 15;
  int row = row_base + r16; if (row >= N) row = N - 1;
  int col = col_base + r16;
  f32x4 acc = {0.f, 0.f, 0.f, 0.f};
  const short8* ap = (const short8*)(aggr + (size_t)row * 160 + quad * 8);
  const short8* bp = (const short8*)(euwT + (size_t)col * 160 + quad * 8);
#pragma unroll
  for (int kk = 0; kk < 5; ++kk) {
    short8 a = ap[kk * 4];
    short8 b = bp[kk * 4];
    acc = __builtin_amdgcn_mfma_f32_16x16x32_bf16(a, b, acc, 0, 0, 0);
  }
  float bv = biasf[col];
  int f = *flag;
#pragma unroll
  for (int r = 0; r < 4; ++r) {
    int node = row_base + quad * 4 + r;
    if (node < N) {
      float v = acc[r] + bv;
      if (f) ((float*)dout)[(size_t)node * 128 + col] = v;
      else   ((bf16*)dout)[(size_t)node * 128 + col] = __float2bfloat16(v);
    }
  }
}

// ------------------------------------------------------------------
extern "C" void kernel_launch(void* const* d_in, const int* in_sizes, int n_in,
                              void* d_out, int out_size, void* d_ws, size_t ws_size,
                              hipStream_t stream) {
  const int* x_idx = (const int*)d_in[0];
  const int* edge_index = (const int*)d_in[1];
  const int* edge_attr_idx = (const int*)d_in[2];

  int N = in_sizes[0];
  int E0 = in_sizes[1] / 2;
  int E = E0 + N;
  const int* src = edge_index;
  const int* dst = edge_index + E0;

  // ---- workspace carve (~12.2 MB) ----
  size_t off = 0;
  char* base = (char*)d_ws;
  auto carve = [&](size_t bytes) -> void* {
    void* p = base + off;
    off += (bytes + 255) & ~(size_t)255;
    return p;
  };
  int* flag     = (int*)carve(256);
  int* counts   = (int*)carve((size_t)N * 4);    // becomes cursor after scan
  int* row_ptr  = (int*)carve((size_t)(N + 1) * 4);
  int* packed   = (int*)carve((size_t)E * 4);
  float* s_i    = (float*)carve((size_t)N * 3 * 4);
  float* s_j    = (float*)carve((size_t)N * 3 * 4);
  float* s_et   = (float*)carve(2 * 65 * 3 * 4);
  float* eef    = (float*)carve(2048 * 4);
  float* att1f  = (float*)carve(864 * 4);
  float* att2f  = (float*)carve(864 * 4);
  float* b1f    = (float*)carve(128 * 4);
  float* b2f_   = (float*)carve(128 * 4);
  bf16* WT1     = (bf16*)carve(49152 * 2);
  bf16* WT2     = (bf16*)carve(49152 * 2);
  bf16* euT1    = (bf16*)carve(20480 * 2);
  bf16* euT2    = (bf16*)carve(20480 * 2);
  bf16* xh      = (bf16*)carve((size_t)N * 384 * 2 + 64);
  bf16* aggr    = (bf16*)carve((size_t)N * 160 * 2);
  bf16* xb      = (bf16*)d_out;  // bf16 x0 lives in d_out
  (void)n_in; (void)out_size; (void)ws_size;

  // ---- setup: 4 dispatches ----
  wconv_kernel<<<(143296 + N + 255) / 256, 256, 0, stream>>>(
      d_in[4], d_in[5], d_in[6], d_in[7], d_in[8], d_in[9], d_in[10], d_in[11],
      d_in[12], flag, eef, att1f, att2f, b1f, b2f_, WT1, WT2, euT1, euT2,
      s_et, counts, N);
  int nb4 = (N + 3) / 4;
  prep_kernel<<<nb4, 256, 0, stream>>>(x_idx, d_in[3], flag, xb, counts, dst,
                                       E0, N);
  scan_kernel<<<1, 1024, 0, stream>>>(counts, row_ptr, N);
  scatter_kernel<<<(E + 255) / 256, 256, 0, stream>>>(src, dst, edge_attr_idx,
                                                      counts, packed, E0, N);

  int nrb16 = (N + 15) / 16;
  int nrb32 = (N + 31) / 32;
  int nb2 = (N + 1) / 2;

  // layer (0,0): W1/att1
  gemm_xh_s_mfma<<<nrb32, 384, 0, stream>>>(xb, WT1, att1f, xh, s_i, s_j, N);
  edge_aggr_kernel<<<nb2, 256, 0, stream>>>(
      (const int*)xh, s_i, s_j, s_et, (const float2*)eef,
      row_ptr, packed, (unsigned*)aggr, N, E);
  // boundary (0,0)->(0,1): euw1+b1+ELU, then W2/att2
  fox_kernel<<<nrb16, 384, 0, stream>>>(aggr, euT1, b1f, 1, WT2, att2f,
                                        xh, s_i, s_j, N);
  edge_aggr_kernel<<<nb2, 256, 0, stream>>>(
      (const int*)xh, s_i, s_j, s_et + 195, (const float2*)eef,
      row_ptr, packed, (unsigned*)aggr, N, E);
  // boundary (0,1)->(1,0): euw2+b2 (no ELU), then W1/att1
  fox_kernel<<<nrb16, 384, 0, stream>>>(aggr, euT2, b2f_, 0, WT1, att1f,
                                        xh, s_i, s_j, N);
  edge_aggr_kernel<<<nb2, 256, 0, stream>>>(
      (const int*)xh, s_i, s_j, s_et, (const float2*)eef,
      row_ptr, packed, (unsigned*)aggr, N, E);
  // boundary (1,0)->(1,1): euw1+b1+ELU, then W2/att2
  fox_kernel<<<nrb16, 384, 0, stream>>>(aggr, euT1, b1f, 1, WT2, att2f,
                                        xh, s_i, s_j, N);
  edge_aggr_kernel<<<nb2, 256, 0, stream>>>(
      (const int*)xh, s_i, s_j, s_et + 195, (const float2*)eef,
      row_ptr, packed, (unsigned*)aggr, N, E);
  // final: euw2+b2, store d_out
  gemm_out_mfma<<<dim3(nrb16, 2), 256, 0, stream>>>(aggr, euT2, b2f_,
                                                    d_out, flag, N);
}